// Round 7
// baseline (178.552 us; speedup 1.0000x reference)
//
#include <hip/hip_runtime.h>
#include <math.h>

// ============================================================================
// MultiHeadDistanceLayer — v5
//  attn: no-max exp-sum softmax (scores bounded, shift-invariance => exact),
//        3-pass bf16-split MFMA QK^T, double-buffered K LDS with 1 barrier
//        per tile (write-other/compute-this), loads issued 2 tiles early,
//        raw v_exp, P-only b32 table + S0/S1 inline-const distance folding.
//  proj: if ws >= 41 MiB: prep (x,W^T -> bf16 hi/lo planes once) + pure-MFMA
//        barrier-free proj. Else: v4 fallback proj (proven).
// ============================================================================

#define B_  4
#define L_  2048
#define D_  256
#define H_  8
#define HD_ 64

typedef unsigned int u32;
typedef unsigned short u16;
typedef short bf16x8 __attribute__((ext_vector_type(8)));
typedef float f32x4  __attribute__((ext_vector_type(4)));

__device__ __forceinline__ u16 bf16rne(float v) {
    u32 u = __float_as_uint(v);
    return (u16)((u + 0x7fffu + ((u >> 16) & 1u)) >> 16);
}
__device__ __forceinline__ float bf2f(u16 h) { return __uint_as_float(((u32)h) << 16); }

#if __has_builtin(__builtin_amdgcn_exp2f)
__device__ __forceinline__ float fast_exp2(float x) { return __builtin_amdgcn_exp2f(x); }
#else
__device__ __forceinline__ float fast_exp2(float x) { return exp2f(x); }
#endif

// ---------------------------------------------------------------------------
// prep (path A only): x -> xhi/xlo bf16 planes [8192][256];
// Wq,Wk -> transposed bf16 planes wt[hi/lo][z*512+n][256].
// grid 1024 (x) + 64 (W tiles), 256 thr.
// ---------------------------------------------------------------------------
__global__ __launch_bounds__(256) void prep_kernel(
    const float* __restrict__ x, const float* __restrict__ Wq, const float* __restrict__ Wk,
    u16* __restrict__ xhi, u16* __restrict__ xlo,
    u16* __restrict__ wthi, u16* __restrict__ wtlo)
{
    __shared__ float Ws[64][65];
    const int t = threadIdx.x;
    if (blockIdx.x < 1024) {
        const size_t base = ((size_t)blockIdx.x * 256 + t) * 8;
        float4 a = *(const float4*)&x[base];
        float4 b = *(const float4*)&x[base + 4];
        float v[8] = {a.x, a.y, a.z, a.w, b.x, b.y, b.z, b.w};
        u32 hp[4], lp[4];
        #pragma unroll
        for (int j = 0; j < 4; ++j) {
            u16 h0 = bf16rne(v[2*j]),   l0 = bf16rne(v[2*j]   - bf2f(bf16rne(v[2*j])));
            u16 h1 = bf16rne(v[2*j+1]), l1 = bf16rne(v[2*j+1] - bf2f(bf16rne(v[2*j+1])));
            hp[j] = (u32)h0 | ((u32)h1 << 16);
            lp[j] = (u32)l0 | ((u32)l1 << 16);
        }
        *(uint4*)&xhi[base] = *(uint4*)hp;
        *(uint4*)&xlo[base] = *(uint4*)lp;
    } else {
        const int widx = blockIdx.x - 1024;          // 0..63
        const int wsel = widx >> 5;                  // 0: Wq, 1: Wk
        const float* W = wsel ? Wk : Wq;
        const int tile = widx & 31;
        const int kt = tile >> 3, nt = tile & 7;     // 4 k-tiles x 8 n-tiles of 64
        const int kr = t >> 2, c4 = t & 3;
        #pragma unroll
        for (int c = 0; c < 4; ++c) {
            float4 v = *(const float4*)&W[(size_t)(kt*64 + kr) * 512 + nt*64 + c4*16 + c*4];
            Ws[kr][c4*16 + c*4 + 0] = v.x; Ws[kr][c4*16 + c*4 + 1] = v.y;
            Ws[kr][c4*16 + c*4 + 2] = v.z; Ws[kr][c4*16 + c*4 + 3] = v.w;
        }
        __syncthreads();
        const int nr = t >> 2;
        const int kc4 = (t & 3) * 16;
        u32 hp[8], lp[8];
        #pragma unroll
        for (int j = 0; j < 8; ++j) {
            float v0 = Ws[kc4 + 2*j][nr], v1 = Ws[kc4 + 2*j + 1][nr];
            u16 h0 = bf16rne(v0), h1 = bf16rne(v1);
            u16 l0 = bf16rne(v0 - bf2f(h0)), l1 = bf16rne(v1 - bf2f(h1));
            hp[j] = (u32)h0 | ((u32)h1 << 16);
            lp[j] = (u32)l0 | ((u32)l1 << 16);
        }
        const size_t ob = ((size_t)wsel*512 + nt*64 + nr) * 256 + kt*64 + kc4;
        *(uint4*)&wthi[ob] = *(uint4*)&hp[0]; *(uint4*)&wthi[ob + 8] = *(uint4*)&hp[4];
        *(uint4*)&wtlo[ob] = *(uint4*)&lp[0]; *(uint4*)&wtlo[ob + 8] = *(uint4*)&lp[4];
    }
}

// ---------------------------------------------------------------------------
// projA (path A): pure-MFMA, no LDS, no barriers. 1-D grid 1024 with XCD
// swizzle grouping same-m-tile blocks per XCD. 4 waves x (32m x 64n).
// ---------------------------------------------------------------------------
__global__ __launch_bounds__(256, 4) void projA_kernel(
    const u16* __restrict__ xhi, const u16* __restrict__ xlo,
    const u16* __restrict__ wthi, const u16* __restrict__ wtlo,
    const float* __restrict__ bq, const float* __restrict__ bk,
    u16* __restrict__ Qhi, u16* __restrict__ Qlo,
    u16* __restrict__ Khi, u16* __restrict__ Klo)
{
    const int p = blockIdx.x;
    const int xcd = p & 7, s = p >> 3;
    const int mx = xcd * 8 + (s & 7);            // 0..63
    const int hz = s >> 3;                       // 0..15
    const int h = hz & 7, z = hz >> 3;

    const float* bias = z ? bk : bq;
    u16* Ohi = z ? Khi : Qhi;
    u16* Olo = z ? Klo : Qlo;

    const int t = threadIdx.x, w = t >> 6, l = t & 63;
    const int kc = l & 15, lhi = l >> 4;
    const int m0 = mx * 128 + w * 32;
    const size_t wb = ((size_t)z * 512 + h * 64) * 256;

    f32x4 acc[2][4];
    #pragma unroll
    for (int mf = 0; mf < 2; ++mf)
        #pragma unroll
        for (int nf = 0; nf < 4; ++nf) acc[mf][nf] = (f32x4){0.f, 0.f, 0.f, 0.f};

    #pragma unroll 2
    for (int ks = 0; ks < 8; ++ks) {
        const int ko = ks * 32 + lhi * 8;
        bf16x8 ah[2], al[2], bh[4], bl[4];
        #pragma unroll
        for (int mf = 0; mf < 2; ++mf) {
            const size_t ao = (size_t)(m0 + mf*16 + kc) * 256 + ko;
            ah[mf] = *(const bf16x8*)&xhi[ao];
            al[mf] = *(const bf16x8*)&xlo[ao];
        }
        #pragma unroll
        for (int nf = 0; nf < 4; ++nf) {
            const size_t bo = wb + (size_t)(nf*16 + kc) * 256 + ko;
            bh[nf] = *(const bf16x8*)&wthi[bo];
            bl[nf] = *(const bf16x8*)&wtlo[bo];
        }
        #pragma unroll
        for (int mf = 0; mf < 2; ++mf)
            #pragma unroll
            for (int nf = 0; nf < 4; ++nf) {
                acc[mf][nf] = __builtin_amdgcn_mfma_f32_16x16x32_bf16(ah[mf], bh[nf], acc[mf][nf], 0, 0, 0);
                acc[mf][nf] = __builtin_amdgcn_mfma_f32_16x16x32_bf16(ah[mf], bl[nf], acc[mf][nf], 0, 0, 0);
                acc[mf][nf] = __builtin_amdgcn_mfma_f32_16x16x32_bf16(al[mf], bh[nf], acc[mf][nf], 0, 0, 0);
            }
    }

    #pragma unroll
    for (int mf = 0; mf < 2; ++mf)
        #pragma unroll
        for (int nf = 0; nf < 4; ++nf) {
            const float bv = bias[h * 64 + nf*16 + kc];
            #pragma unroll
            for (int r = 0; r < 4; ++r) {
                const float v = acc[mf][nf][r] + bv;
                const u16 hi = bf16rne(v);
                const u16 lo = bf16rne(v - bf2f(hi));
                const int m = m0 + mf*16 + lhi*4 + r;
                const int bb = m >> 11, ll = m & (L_ - 1);
                const size_t o = (((size_t)h * B_ + bb) * L_ + ll) * HD_ + nf*16 + kc;
                Ohi[o] = hi; Olo[o] = lo;
            }
        }
}

// ---------------------------------------------------------------------------
// projB (fallback, proven v4): fp32 x/W with per-ks LDS W transpose.
// ---------------------------------------------------------------------------
__global__ __launch_bounds__(256, 4) void projB_kernel(
    const float* __restrict__ x,
    const float* __restrict__ Wq, const float* __restrict__ bq,
    const float* __restrict__ Wk, const float* __restrict__ bk,
    u16* __restrict__ Qhi, u16* __restrict__ Qlo,
    u16* __restrict__ Khi, u16* __restrict__ Klo)
{
    __shared__ __align__(16) u16 Bs[2][64][40];

    const int z = blockIdx.z;
    const float* W    = z ? Wk : Wq;
    const float* bias = z ? bk : bq;
    u16* Ohi = z ? Khi : Qhi;
    u16* Olo = z ? Klo : Qlo;

    const int t = threadIdx.x, w = t >> 6, l = t & 63;
    const int kc = l & 15, lhi = l >> 4;
    const int m0 = blockIdx.x * 128 + w * 32;
    const int h  = blockIdx.y;

    const float* xp0 = x + (size_t)(m0 + kc) * D_;
    const float* xp1 = x + (size_t)(m0 + 16 + kc) * D_;

    f32x4 acc[2][4];
    #pragma unroll
    for (int mf = 0; mf < 2; ++mf)
        #pragma unroll
        for (int nf = 0; nf < 4; ++nf) acc[mf][nf] = (f32x4){0.f, 0.f, 0.f, 0.f};

    for (int ks = 0; ks < 8; ++ks) {
        __syncthreads();
        #pragma unroll
        for (int j = 0; j < 2; ++j) {
            const int fid = t + j * 256;
            const int kr = fid >> 4, c4 = fid & 15;
            float4 v = *(const float4*)&W[(size_t)(ks*32 + kr) * 512 + h*64 + c4*4];
            float vv[4] = {v.x, v.y, v.z, v.w};
            #pragma unroll
            for (int e = 0; e < 4; ++e) {
                const int n = c4*4 + e;
                const u16 hi = bf16rne(vv[e]);
                Bs[0][n][kr] = hi;
                Bs[1][n][kr] = bf16rne(vv[e] - bf2f(hi));
            }
        }
        __syncthreads();

        union { u16 u[8]; bf16x8 v; } ah[2], al[2];
        #pragma unroll
        for (int mf = 0; mf < 2; ++mf) {
            const float* xp = mf ? xp1 : xp0;
            float4 a = *(const float4*)(xp + ks*32 + lhi*8);
            float4 b = *(const float4*)(xp + ks*32 + lhi*8 + 4);
            float vv[8] = {a.x, a.y, a.z, a.w, b.x, b.y, b.z, b.w};
            #pragma unroll
            for (int e = 0; e < 8; ++e) {
                const u16 hi = bf16rne(vv[e]);
                ah[mf].u[e] = hi;
                al[mf].u[e] = bf16rne(vv[e] - bf2f(hi));
            }
        }

        #pragma unroll
        for (int nf = 0; nf < 4; ++nf) {
            const bf16x8 bh = *(const bf16x8*)&Bs[0][nf*16 + kc][lhi*8];
            const bf16x8 bl = *(const bf16x8*)&Bs[1][nf*16 + kc][lhi*8];
            #pragma unroll
            for (int mf = 0; mf < 2; ++mf) {
                acc[mf][nf] = __builtin_amdgcn_mfma_f32_16x16x32_bf16(ah[mf].v, bh, acc[mf][nf], 0, 0, 0);
                acc[mf][nf] = __builtin_amdgcn_mfma_f32_16x16x32_bf16(ah[mf].v, bl, acc[mf][nf], 0, 0, 0);
                acc[mf][nf] = __builtin_amdgcn_mfma_f32_16x16x32_bf16(al[mf].v, bh, acc[mf][nf], 0, 0, 0);
            }
        }
    }

    #pragma unroll
    for (int mf = 0; mf < 2; ++mf)
        #pragma unroll
        for (int nf = 0; nf < 4; ++nf) {
            const float bv = bias[h * 64 + nf*16 + kc];
            #pragma unroll
            for (int r = 0; r < 4; ++r) {
                const float v = acc[mf][nf][r] + bv;
                const u16 hi = bf16rne(v);
                const u16 lo = bf16rne(v - bf2f(hi));
                const int m = m0 + mf*16 + lhi*4 + r;
                const int bb = m >> 11, ll = m & (L_ - 1);
                const size_t o = (((size_t)h * B_ + bb) * L_ + ll) * HD_ + nf*16 + kc;
                Ohi[o] = hi; Olo[o] = lo;
            }
        }
}

// ---------------------------------------------------------------------------
// attn: 512 blocks (XCD-grouped: 4 hb per XCD), 512 thr = 8 waves x 16 q.
// Double-buffered K LDS, loads 2 tiles ahead, ONE barrier per tile.
// ---------------------------------------------------------------------------
__global__ __launch_bounds__(512, 4) void attn_kernel(
    const u16* __restrict__ Qhi, const u16* __restrict__ Qlo,
    const u16* __restrict__ Khi, const u16* __restrict__ Klo,
    const float* __restrict__ prior_mean, const float* __restrict__ log_prior_std,
    const int* __restrict__ max_len, float* __restrict__ out)
{
    __shared__ __align__(16) u16 kls[2][2][64 * 64];   // [buf][plane], 32 KB
    __shared__ float Ptab[2176];                       // P*0.125*log2e, 8.7 KB

    const int t = threadIdx.x, w = t >> 6, l = t & 63;
    const int kc = l & 15, lhi = l >> 4;

    const int p = blockIdx.x;                 // XCD-grouped decode
    const int xcd = p & 7, s = p >> 3;
    const int hb = xcd * 4 + (s >> 4);
    const int q0 = (s & 15) * 128;
    const int h = hb >> 2, b = hb & 3;
    const int qw = q0 + w * 16;

    const float iml = 1.0f / (float)(*max_len);
    const float mu  = prior_mean[h];
    const float sg  = __expf(log_prior_std[h]);
    const float isg = 1.0f / sg;
    const float coef = 0.125f * 1.44269504089f / (sg * 2.5066282746310002f);
    for (int i = t; i < 2175; i += 512) {
        const float dist = (float)(i - q0 - 127) * iml;
        const float tt = (dist - mu) * isg;
        Ptab[i] = coef * __expf(-0.5f * tt * tt);
    }

    bf16x8 qh[2], ql2[2];
    #pragma unroll
    for (int dh = 0; dh < 2; ++dh) {
        const size_t qo = ((size_t)hb * L_ + qw + kc) * HD_ + dh*32 + lhi*8;
        qh[dh]  = *(const bf16x8*)&Qhi[qo];
        ql2[dh] = *(const bf16x8*)&Qlo[qo];
    }

    const float* pb = &Ptab[lhi*4 + 127 - w*16 - kc];
    const float dqf = (float)(lhi*4 - qw - kc);

    // staging: 512 thr cover 2 planes x 64 rows x 4 quarters
    const int spl = t >> 8;
    const int srow = (t & 255) >> 2;
    const int sq = t & 3;
    const int sr7 = srow & 7;
    const u16* Kg = (spl ? Klo : Khi) + ((size_t)hb * L_ + srow) * HD_ + sq * 16;
    const int p0 = ((sq*2)     ^ sr7) * 8;
    const int p1 = ((sq*2 + 1) ^ sr7) * 8;
    u16* wdst0 = &kls[0][spl][srow * 64];
    u16* wdst1 = &kls[1][spl][srow * 64];

    const int sl0 = (lhi ^ (kc & 7)) * 8;
    const int sl1 = ((4 + lhi) ^ (kc & 7)) * 8;

    float lv = 0.f, wvs = 0.f;

    uint4 ra0, ra1, rb0, rb1;
    // prologue: tile0 -> buf0; tile1 -> regs A
    ra0 = *(const uint4*)Kg; ra1 = *(const uint4*)(Kg + 8);
    *(uint4*)&wdst0[p0] = ra0; *(uint4*)&wdst0[p1] = ra1;
    ra0 = *(const uint4*)(Kg + 4096); ra1 = *(const uint4*)(Kg + 4096 + 8);
    __syncthreads();

#define LOADT(RX0, RX1, TI) { const u16* src_ = Kg + (size_t)(TI) * 4096; \
    RX0 = *(const uint4*)src_; RX1 = *(const uint4*)(src_ + 8); }
#define WRT(DST, RX0, RX1) { *(uint4*)&DST[p0] = RX0; *(uint4*)&DST[p1] = RX1; }
#define CTILE(TI, BS) { \
    const u16* bh_ = &kls[BS][0][0]; const u16* bl_ = &kls[BS][1][0]; \
    f32x4 acc[4]; \
    _Pragma("unroll") for (int kf = 0; kf < 4; ++kf) acc[kf] = (f32x4){0.f,0.f,0.f,0.f}; \
    __builtin_amdgcn_s_setprio(1); \
    _Pragma("unroll") for (int kf = 0; kf < 4; ++kf) { \
        const int rb_ = (kf*16 + kc) * 64; \
        const bf16x8 ah0 = *(const bf16x8*)&bh_[rb_ + sl0]; \
        const bf16x8 ah1 = *(const bf16x8*)&bh_[rb_ + sl1]; \
        const bf16x8 al0 = *(const bf16x8*)&bl_[rb_ + sl0]; \
        const bf16x8 al1 = *(const bf16x8*)&bl_[rb_ + sl1]; \
        acc[kf] = __builtin_amdgcn_mfma_f32_16x16x32_bf16(ah0, qh[0],  acc[kf], 0, 0, 0); \
        acc[kf] = __builtin_amdgcn_mfma_f32_16x16x32_bf16(ah1, qh[1],  acc[kf], 0, 0, 0); \
        acc[kf] = __builtin_amdgcn_mfma_f32_16x16x32_bf16(ah0, ql2[0], acc[kf], 0, 0, 0); \
        acc[kf] = __builtin_amdgcn_mfma_f32_16x16x32_bf16(ah1, ql2[1], acc[kf], 0, 0, 0); \
        acc[kf] = __builtin_amdgcn_mfma_f32_16x16x32_bf16(al0, qh[0],  acc[kf], 0, 0, 0); \
        acc[kf] = __builtin_amdgcn_mfma_f32_16x16x32_bf16(al1, qh[1],  acc[kf], 0, 0, 0); \
    } \
    __builtin_amdgcn_s_setprio(0); \
    const float* pp = pb + (TI) * 64; \
    float S0 = 0.f, S1 = 0.f; \
    _Pragma("unroll") for (int kf = 0; kf < 4; ++kf) \
        _Pragma("unroll") for (int r = 0; r < 4; ++r) { \
            const int cc = kf*16 + r; \
            const float e = fast_exp2(acc[kf][r] * pp[cc]); \
            S0 += e; if (cc) S1 = fmaf(e, (float)cc, S1); \
        } \
    lv += S0; \
    wvs = fmaf((float)((TI) << 6) + dqf, S0, wvs + S1); \
}

    for (int kt = 0; kt < 32; kt += 2) {
        // even half: write tile kt+1 -> buf1, compute tile kt from buf0
        if (kt + 2 < 32) LOADT(rb0, rb1, kt + 2);
        WRT(wdst1, ra0, ra1);
        CTILE(kt, 0);
        __syncthreads();
        // odd half: write tile kt+2 -> buf0, compute tile kt+1 from buf1
        if (kt + 3 < 32) LOADT(ra0, ra1, kt + 3);
        if (kt + 2 < 32) WRT(wdst0, rb0, rb1);
        CTILE(kt + 1, 1);
        __syncthreads();
    }
#undef LOADT
#undef WRT
#undef CTILE

    lv  += __shfl_xor(lv, 16);  wvs += __shfl_xor(wvs, 16);
    lv  += __shfl_xor(lv, 32);  wvs += __shfl_xor(wvs, 32);
    if (lhi == 0) {
        const int q = qw + kc;
        out[((size_t)(b * L_ + q)) * H_ + h] = (wvs * iml) / lv;
    }
}

// ---------------------------------------------------------------------------
extern "C" void kernel_launch(void* const* d_in, const int* in_sizes, int n_in,
                              void* d_out, int out_size, void* d_ws, size_t ws_size,
                              hipStream_t stream)
{
    const float* x   = (const float*)d_in[0];
    const float* Wq  = (const float*)d_in[1];
    const float* bq  = (const float*)d_in[2];
    const float* Wk  = (const float*)d_in[3];
    const float* bk  = (const float*)d_in[4];
    const float* pm  = (const float*)d_in[5];
    const float* lps = (const float*)d_in[6];
    const int*   mlp = (const int*)d_in[7];
    float* out = (float*)d_out;

    u16* Qhi = (u16*)d_ws;                   // 4 planes x 8 MiB = 32 MiB
    u16* Qlo = Qhi + 4194304;
    u16* Khi = Qlo + 4194304;
    u16* Klo = Khi + 4194304;

    if (ws_size >= (size_t)41 * 1024 * 1024) {
        u16* xhi  = Klo + 4194304;           // +8 MiB x planes, +1 MiB W^T
        u16* xlo  = xhi + 2097152;
        u16* wthi = xlo + 2097152;
        u16* wtlo = wthi + 262144;
        prep_kernel<<<dim3(1088), 256, 0, stream>>>(x, Wq, Wk, xhi, xlo, wthi, wtlo);
        projA_kernel<<<dim3(1024), 256, 0, stream>>>(xhi, xlo, wthi, wtlo, bq, bk,
                                                     Qhi, Qlo, Khi, Klo);
    } else {
        projB_kernel<<<dim3(64, 8, 2), 256, 0, stream>>>(x, Wq, bq, Wk, bk,
                                                         Qhi, Qlo, Khi, Klo);
    }
    attn_kernel<<<dim3(512), 512, 0, stream>>>(Qhi, Qlo, Khi, Klo, pm, lps, mlp, out);
}

// Round 8
// 169.542 us; speedup vs baseline: 1.0531x; 1.0531x over previous
//
#include <hip/hip_runtime.h>
#include <math.h>

// ============================================================================
// MultiHeadDistanceLayer — v6
//  attn (LDS-BW-bound fix): 512 thr = 8 waves x 32 q/wave (q-tile 256),
//    grid 256 (1 block/CU). K-tile 64 staged hi/lo to LDS (XOR swizzle),
//    double-buffered, loads 2 tiles ahead, 1 barrier/tile. Prior computed
//    INLINE (exp2 chain) -> zero LDS gather. No-max softmax (scores bounded).
//    LDS bytes/kernel: 1.18 GB -> ~23 us floor (was 2.88 GB -> 55+ us).
//  proj: v4-proven projB (fp32 x/W, per-ks LDS W transpose, 3-pass bf16 MFMA).
// ============================================================================

#define B_  4
#define L_  2048
#define D_  256
#define H_  8
#define HD_ 64

typedef unsigned int u32;
typedef unsigned short u16;
typedef short bf16x8 __attribute__((ext_vector_type(8)));
typedef float f32x4  __attribute__((ext_vector_type(4)));

__device__ __forceinline__ u16 bf16rne(float v) {
    u32 u = __float_as_uint(v);
    return (u16)((u + 0x7fffu + ((u >> 16) & 1u)) >> 16);
}
__device__ __forceinline__ float bf2f(u16 h) { return __uint_as_float(((u32)h) << 16); }

#if __has_builtin(__builtin_amdgcn_exp2f)
__device__ __forceinline__ float fast_exp2(float x) { return __builtin_amdgcn_exp2f(x); }
#else
__device__ __forceinline__ float fast_exp2(float x) { return exp2f(x); }
#endif

// ---------------------------------------------------------------------------
// projB (proven v4): Q/K = x@W + b, 3-pass bf16 MFMA, per-ks LDS W transpose.
// grid (64 m-tiles of 128, 8 heads, 2 {Q,K}), 256 thr.
// ---------------------------------------------------------------------------
__global__ __launch_bounds__(256, 4) void projB_kernel(
    const float* __restrict__ x,
    const float* __restrict__ Wq, const float* __restrict__ bq,
    const float* __restrict__ Wk, const float* __restrict__ bk,
    u16* __restrict__ Qhi, u16* __restrict__ Qlo,
    u16* __restrict__ Khi, u16* __restrict__ Klo)
{
    __shared__ __align__(16) u16 Bs[2][64][40];

    const int z = blockIdx.z;
    const float* W    = z ? Wk : Wq;
    const float* bias = z ? bk : bq;
    u16* Ohi = z ? Khi : Qhi;
    u16* Olo = z ? Klo : Qlo;

    const int t = threadIdx.x, w = t >> 6, l = t & 63;
    const int kc = l & 15, lhi = l >> 4;
    const int m0 = blockIdx.x * 128 + w * 32;
    const int h  = blockIdx.y;

    const float* xp0 = x + (size_t)(m0 + kc) * D_;
    const float* xp1 = x + (size_t)(m0 + 16 + kc) * D_;

    f32x4 acc[2][4];
    #pragma unroll
    for (int mf = 0; mf < 2; ++mf)
        #pragma unroll
        for (int nf = 0; nf < 4; ++nf) acc[mf][nf] = (f32x4){0.f, 0.f, 0.f, 0.f};

    for (int ks = 0; ks < 8; ++ks) {
        __syncthreads();
        #pragma unroll
        for (int j = 0; j < 2; ++j) {
            const int fid = t + j * 256;
            const int kr = fid >> 4, c4 = fid & 15;
            float4 v = *(const float4*)&W[(size_t)(ks*32 + kr) * 512 + h*64 + c4*4];
            float vv[4] = {v.x, v.y, v.z, v.w};
            #pragma unroll
            for (int e = 0; e < 4; ++e) {
                const int n = c4*4 + e;
                const u16 hi = bf16rne(vv[e]);
                Bs[0][n][kr] = hi;
                Bs[1][n][kr] = bf16rne(vv[e] - bf2f(hi));
            }
        }
        __syncthreads();

        union { u16 u[8]; bf16x8 v; } ah[2], al[2];
        #pragma unroll
        for (int mf = 0; mf < 2; ++mf) {
            const float* xp = mf ? xp1 : xp0;
            float4 a = *(const float4*)(xp + ks*32 + lhi*8);
            float4 b = *(const float4*)(xp + ks*32 + lhi*8 + 4);
            float vv[8] = {a.x, a.y, a.z, a.w, b.x, b.y, b.z, b.w};
            #pragma unroll
            for (int e = 0; e < 8; ++e) {
                const u16 hi = bf16rne(vv[e]);
                ah[mf].u[e] = hi;
                al[mf].u[e] = bf16rne(vv[e] - bf2f(hi));
            }
        }

        #pragma unroll
        for (int nf = 0; nf < 4; ++nf) {
            const bf16x8 bh = *(const bf16x8*)&Bs[0][nf*16 + kc][lhi*8];
            const bf16x8 bl = *(const bf16x8*)&Bs[1][nf*16 + kc][lhi*8];
            #pragma unroll
            for (int mf = 0; mf < 2; ++mf) {
                acc[mf][nf] = __builtin_amdgcn_mfma_f32_16x16x32_bf16(ah[mf].v, bh, acc[mf][nf], 0, 0, 0);
                acc[mf][nf] = __builtin_amdgcn_mfma_f32_16x16x32_bf16(ah[mf].v, bl, acc[mf][nf], 0, 0, 0);
                acc[mf][nf] = __builtin_amdgcn_mfma_f32_16x16x32_bf16(al[mf].v, bh, acc[mf][nf], 0, 0, 0);
            }
        }
    }

    #pragma unroll
    for (int mf = 0; mf < 2; ++mf)
        #pragma unroll
        for (int nf = 0; nf < 4; ++nf) {
            const float bv = bias[h * 64 + nf*16 + kc];
            #pragma unroll
            for (int r = 0; r < 4; ++r) {
                const float v = acc[mf][nf][r] + bv;
                const u16 hi = bf16rne(v);
                const u16 lo = bf16rne(v - bf2f(hi));
                const int m = m0 + mf*16 + lhi*4 + r;
                const int bb = m >> 11, ll = m & (L_ - 1);
                const size_t o = (((size_t)h * B_ + bb) * L_ + ll) * HD_ + nf*16 + kc;
                Ohi[o] = hi; Olo[o] = lo;
            }
        }
}

// ---------------------------------------------------------------------------
// attn v6: grid 256 (8 q-tiles of 256 x 32 hb, XCD-grouped), 512 thr = 8 waves,
// 32 q per wave (2 qf x 16). A=K(LDS), B=Q(regs). Inline gaussian prior.
// ---------------------------------------------------------------------------
__global__ __launch_bounds__(512, 2) void attn_kernel(
    const u16* __restrict__ Qhi, const u16* __restrict__ Qlo,
    const u16* __restrict__ Khi, const u16* __restrict__ Klo,
    const float* __restrict__ prior_mean, const float* __restrict__ log_prior_std,
    const int* __restrict__ max_len, float* __restrict__ out)
{
    __shared__ __align__(16) u16 kls[2][2][64 * 64];   // [buf][plane], 32 KB total

    const int t = threadIdx.x, w = t >> 6, l = t & 63;
    const int kc = l & 15, lhi = l >> 4;

    const int p = blockIdx.x;                 // XCD-grouped decode: 32 blk/XCD
    const int xcd = p & 7, s = p >> 3;        // s in [0,32)
    const int hb = xcd * 4 + (s >> 3);        // 4 hb per XCD
    const int q0 = (s & 7) * 256;             // 8 q-tiles of 256
    const int h = hb >> 2, b = hb & 3;
    const int qw = q0 + w * 32;

    const float iml = 1.0f / (float)(*max_len);
    const float mu  = prior_mean[h];
    const float sg  = __expf(log_prior_std[h]);
    const float isg = 1.0f / sg;
    // p = exp2(LC - t2^2), t2 = delta*A2 + B2  => P*0.125*log2e
    const float S2  = 0.84932180f;                       // sqrt(0.5*log2e)
    const float A2  = iml * isg * S2;
    const float B2  = -mu * isg * S2;
    const float LC  = __log2f(0.125f * 1.44269504089f / (sg * 2.5066282746310002f));

    // ---- Q fragments: [qf][dh] hi and lo ----
    bf16x8 qh[2][2], ql2[2][2];
    #pragma unroll
    for (int qf = 0; qf < 2; ++qf)
        #pragma unroll
        for (int dh = 0; dh < 2; ++dh) {
            const size_t qo = ((size_t)hb * L_ + qw + qf*16 + kc) * HD_ + dh*32 + lhi*8;
            qh[qf][dh]  = *(const bf16x8*)&Qhi[qo];
            ql2[qf][dh] = *(const bf16x8*)&Qlo[qo];
        }

    // delta bases: delta = TI*64 + cc + d0q[qf]
    const int d0q0 = lhi*4 - (q0 + w*32 + kc);
    const int d0q1 = d0q0 - 16;

    // ---- staging: 512 thr = 2 planes x 64 rows x 2 halves, 2x uint4 each ----
    const int spl = t >> 8;
    const int srow = (t & 255) >> 2;
    const int sq = t & 3;
    const int sr7 = srow & 7;
    const u16* Kg = (spl ? Klo : Khi) + ((size_t)hb * L_ + srow) * HD_ + sq * 16;
    const int p0 = ((sq*2)     ^ sr7) * 8;
    const int p1 = ((sq*2 + 1) ^ sr7) * 8;
    u16* wdst0 = &kls[0][spl][srow * 64];
    u16* wdst1 = &kls[1][spl][srow * 64];

    const int sl0 = (lhi ^ (kc & 7)) * 8;
    const int sl1 = ((4 + lhi) ^ (kc & 7)) * 8;

    float lv0 = 0.f, wv0 = 0.f, lv1 = 0.f, wv1 = 0.f;

    uint4 ra0, ra1, rb0, rb1;
    // prologue: tile0 -> buf0; tile1 -> regs A
    ra0 = *(const uint4*)Kg; ra1 = *(const uint4*)(Kg + 8);
    *(uint4*)&wdst0[p0] = ra0; *(uint4*)&wdst0[p1] = ra1;
    ra0 = *(const uint4*)(Kg + 4096); ra1 = *(const uint4*)(Kg + 4096 + 8);
    __syncthreads();

#define LOADT(RX0, RX1, TI) { const u16* src_ = Kg + (size_t)(TI) * 4096; \
    RX0 = *(const uint4*)src_; RX1 = *(const uint4*)(src_ + 8); }
#define WRT(DST, RX0, RX1) { *(uint4*)&DST[p0] = RX0; *(uint4*)&DST[p1] = RX1; }
#define CTILE(TI, BS) { \
    const u16* bh_ = &kls[BS][0][0]; const u16* bl_ = &kls[BS][1][0]; \
    f32x4 acc[4][2]; \
    _Pragma("unroll") for (int kf = 0; kf < 4; ++kf) { \
        acc[kf][0] = (f32x4){0.f,0.f,0.f,0.f}; acc[kf][1] = (f32x4){0.f,0.f,0.f,0.f}; } \
    __builtin_amdgcn_s_setprio(1); \
    _Pragma("unroll") for (int kf = 0; kf < 4; ++kf) { \
        const int rb_ = (kf*16 + kc) * 64; \
        const bf16x8 ah0 = *(const bf16x8*)&bh_[rb_ + sl0]; \
        const bf16x8 ah1 = *(const bf16x8*)&bh_[rb_ + sl1]; \
        const bf16x8 al0 = *(const bf16x8*)&bl_[rb_ + sl0]; \
        const bf16x8 al1 = *(const bf16x8*)&bl_[rb_ + sl1]; \
        _Pragma("unroll") for (int qf = 0; qf < 2; ++qf) { \
            acc[kf][qf] = __builtin_amdgcn_mfma_f32_16x16x32_bf16(ah0, qh[qf][0],  acc[kf][qf], 0, 0, 0); \
            acc[kf][qf] = __builtin_amdgcn_mfma_f32_16x16x32_bf16(ah1, qh[qf][1],  acc[kf][qf], 0, 0, 0); \
            acc[kf][qf] = __builtin_amdgcn_mfma_f32_16x16x32_bf16(ah0, ql2[qf][0], acc[kf][qf], 0, 0, 0); \
            acc[kf][qf] = __builtin_amdgcn_mfma_f32_16x16x32_bf16(ah1, ql2[qf][1], acc[kf][qf], 0, 0, 0); \
            acc[kf][qf] = __builtin_amdgcn_mfma_f32_16x16x32_bf16(al0, qh[qf][0],  acc[kf][qf], 0, 0, 0); \
            acc[kf][qf] = __builtin_amdgcn_mfma_f32_16x16x32_bf16(al1, qh[qf][1],  acc[kf][qf], 0, 0, 0); \
        } \
    } \
    __builtin_amdgcn_s_setprio(0); \
    _Pragma("unroll") for (int qf = 0; qf < 2; ++qf) { \
        const float dbf = (float)((TI)*64 + (qf ? d0q1 : d0q0)); \
        const float t2b = fmaf(dbf, A2, B2); \
        float S0 = 0.f, S1 = 0.f; \
        _Pragma("unroll") for (int kf = 0; kf < 4; ++kf) \
            _Pragma("unroll") for (int r = 0; r < 4; ++r) { \
                const int cc = kf*16 + r; \
                const float t2c = fmaf((float)cc, A2, t2b); \
                const float pr  = fast_exp2(fmaf(-t2c, t2c, LC)); \
                const float e   = fast_exp2(acc[kf][qf][r] * pr); \
                S0 += e; if (cc) S1 = fmaf(e, (float)cc, S1); \
            } \
        if (qf == 0) { lv0 += S0; wv0 = fmaf(dbf, S0, wv0 + S1); } \
        else         { lv1 += S0; wv1 = fmaf(dbf, S0, wv1 + S1); } \
    } \
}

    for (int kt = 0; kt < 32; kt += 2) {
        // even half: write tile kt+1 -> buf1, compute tile kt from buf0
        if (kt + 2 < 32) LOADT(rb0, rb1, kt + 2);
        WRT(wdst1, ra0, ra1);
        CTILE(kt, 0);
        __syncthreads();
        // odd half: write tile kt+2 -> buf0, compute tile kt+1 from buf1
        if (kt + 3 < 32) LOADT(ra0, ra1, kt + 3);
        if (kt + 2 < 32) WRT(wdst0, rb0, rb1);
        CTILE(kt + 1, 1);
        __syncthreads();
    }
#undef LOADT
#undef WRT
#undef CTILE

    // reduce across lhi groups (k-direction): xor lanes 16, 32
    lv0 += __shfl_xor(lv0, 16); wv0 += __shfl_xor(wv0, 16);
    lv0 += __shfl_xor(lv0, 32); wv0 += __shfl_xor(wv0, 32);
    lv1 += __shfl_xor(lv1, 16); wv1 += __shfl_xor(wv1, 16);
    lv1 += __shfl_xor(lv1, 32); wv1 += __shfl_xor(wv1, 32);

    if (lhi == 0) {
        const int q = qw + kc;
        out[((size_t)(b * L_ + q)) * H_ + h] = (wv0 * iml) / lv0;
    } else if (lhi == 1) {
        const int q = qw + 16 + kc;
        out[((size_t)(b * L_ + q)) * H_ + h] = (wv1 * iml) / lv1;
    }
}

// ---------------------------------------------------------------------------
extern "C" void kernel_launch(void* const* d_in, const int* in_sizes, int n_in,
                              void* d_out, int out_size, void* d_ws, size_t ws_size,
                              hipStream_t stream)
{
    const float* x   = (const float*)d_in[0];
    const float* Wq  = (const float*)d_in[1];
    const float* bq  = (const float*)d_in[2];
    const float* Wk  = (const float*)d_in[3];
    const float* bk  = (const float*)d_in[4];
    const float* pm  = (const float*)d_in[5];
    const float* lps = (const float*)d_in[6];
    const int*   mlp = (const int*)d_in[7];
    float* out = (float*)d_out;

    u16* Qhi = (u16*)d_ws;                   // 4 planes x 8 MiB = 32 MiB (proven)
    u16* Qlo = Qhi + 4194304;
    u16* Khi = Qlo + 4194304;
    u16* Klo = Khi + 4194304;

    projB_kernel<<<dim3(64, 8, 2), 256, 0, stream>>>(x, Wq, bq, Wk, bk,
                                                     Qhi, Qlo, Khi, Klo);
    attn_kernel<<<dim3(256), 512, 0, stream>>>(Qhi, Qlo, Khi, Klo, pm, lps, mlp, out);
}